// Round 3
// baseline (344.284 us; speedup 1.0000x reference)
//
#include <hip/hip_runtime.h>
#include <hip/hip_bf16.h>

#define B_  4
#define L_  4096
#define DM_ 1024
#define DK_ 128
#define DV_ 128
#define KS_ 4
#define ROWS_ (B_ * L_)            // 16384

typedef __bf16 bf16x8 __attribute__((ext_vector_type(8)));
typedef float  f32x4  __attribute__((ext_vector_type(4)));

// async global->LDS DMA, 16 B per lane, no VGPR round-trip.
// LDS dest is wave-uniform base + lane*16; gsrc is per-lane.
__device__ __forceinline__ void dma16(const void* g, void* l) {
    __builtin_amdgcn_global_load_lds(
        (const __attribute__((address_space(1))) void*)g,
        (__attribute__((address_space(3))) void*)l, 16, 0, 0);
}

// order-independent: drain ALL vmem (DMAs + any reg prefetch) + LDS, barrier.
#define WAITBAR0() __asm__ volatile("s_waitcnt vmcnt(0) lgkmcnt(0)\ns_barrier" ::: "memory")

// max-reduce over the 16-lane group via DPP row_ror (pure VALU)
__device__ __forceinline__ float rowmax_dpp(float v) {
    int x;
    x = __float_as_int(v);
    v = fmaxf(v, __int_as_float(__builtin_amdgcn_update_dpp(x, x, 0x121, 0xF, 0xF, false)));
    x = __float_as_int(v);
    v = fmaxf(v, __int_as_float(__builtin_amdgcn_update_dpp(x, x, 0x122, 0xF, 0xF, false)));
    x = __float_as_int(v);
    v = fmaxf(v, __int_as_float(__builtin_amdgcn_update_dpp(x, x, 0x124, 0xF, 0xF, false)));
    x = __float_as_int(v);
    v = fmaxf(v, __int_as_float(__builtin_amdgcn_update_dpp(x, x, 0x128, 0xF, 0xF, false)));
    return v;
}

// ---------------------------------------------------------------------------
// Kernel 0: transpose+cast W -> WT bf16; WQ pre-scaled by 1/sqrt(dk).
// ---------------------------------------------------------------------------
__global__ __launch_bounds__(256) void wt_kernel(
    const float* __restrict__ WQ, const float* __restrict__ WK,
    const float* __restrict__ WV, __bf16* __restrict__ WT)
{
    const int mat = blockIdx.y;
    const float* W = (mat == 0) ? WQ : (mat == 1) ? WK : WV;
    const float scl = (mat == 0) ? 0.088388347648318447f : 1.0f;
    __bf16* Wt = WT + (size_t)mat * DK_ * DM_;

    __shared__ float lds[DK_][33];
    const int t  = threadIdx.x;
    const int d0 = blockIdx.x * 32;

    for (int i = 0; i < 16; ++i) {
        int idx = i * 256 + t;
        int dd = idx >> 7, n = idx & 127;
        lds[n][dd] = W[(size_t)(d0 + dd) * DK_ + n] * scl;
    }
    __syncthreads();
    for (int i = 0; i < 16; ++i) {
        int idx = i * 256 + t;
        int n = idx >> 5, dd = idx & 31;
        Wt[(size_t)n * DM_ + d0 + dd] = (__bf16)lds[n][dd];
    }
}

// ---------------------------------------------------------------------------
// Kernel 1: projections — BARRIER-FREE, LDS-FREE. R1 post-mortem: perf was
// insensitive to pipeline depth (depth-2 vmcnt(0) == depth-3 vmcnt(8)), all
// pipes <6% -> the lockstep s_barrier coupling (3 blocks/CU = 3 independent
// streams) was the bottleneck, not memory completion. W is 256 KB/mat and
// shared by every block -> read fragments DIRECTLY from global (16 rows x
// 64 B contiguous per instr, L1/L2-broadcast); each wave runs free. W frags
// double-buffered in regs at half-step granularity; X prefetched 2 chunks
// ahead. Full unroll keeps all buffer indices static (rule #20). No asm:
// compiler schedules its own counted vmcnt with no barrier to drain.
// ---------------------------------------------------------------------------
__global__ __launch_bounds__(256, 3) void proj_kernel(
    const float* __restrict__ Q, const float* __restrict__ K, const float* __restrict__ V,
    const __bf16* __restrict__ WT,
    __bf16* __restrict__ qb, __bf16* __restrict__ kb, __bf16* __restrict__ vT)
{
    const int mat = blockIdx.y;
    const float* X = (mat == 0) ? Q : (mat == 1) ? K : V;
    const __bf16* Wt = WT + (size_t)mat * DK_ * DM_;

    const int t    = threadIdx.x;
    const int w    = t >> 6;
    const int l    = t & 63;
    const int quad = l >> 4;
    const int c16  = l & 15;
    const int m0   = blockIdx.x * 64 + w * 16;
    const float* xrow = &X[(size_t)(m0 + c16) * DM_];

    // per-lane W fragment bases, one per nt; frag (kt,dd) is at element
    // offset kt*64 + dd*32 (byte offset <= 1984, folds into 13-bit imm).
    // frag(nt,kt,dd) = Wt[nt*16+c16][kt*64 + dd*32 + quad*8 .. +8] --
    // identical values to the old LDS-swizzle path.
    const __bf16* wp[8];
    for (int nt = 0; nt < 8; ++nt)
        wp[nt] = Wt + (size_t)(nt * 16 + c16) * DM_ + quad * 8;

    f32x4 acc[8];
    for (int i = 0; i < 8; ++i) acc[i] = {0.f, 0.f, 0.f, 0.f};

    bf16x8 wf[2][8];          // half-step double buffer (static idx: cur==dd)
    float4 xn[2][4];          // 2-chunk-deep X prefetch

    // prologue: W frags for half-step 0; X chunks 0 and 1
    for (int nt = 0; nt < 8; ++nt)
        wf[0][nt] = *(const bf16x8*)(wp[nt]);
    for (int c = 0; c < 2; ++c)
        for (int dd = 0; dd < 2; ++dd)
            for (int p = 0; p < 2; ++p)
                xn[c][dd * 2 + p] = *(const float4*)(xrow + c * 64 + dd * 32 + quad * 8 + p * 4);

#pragma unroll
    for (int kt = 0; kt < 16; ++kt) {             // BK = 64
        float4 xc[4];
        for (int i = 0; i < 4; ++i) xc[i] = xn[kt & 1][i];   // consume
        if (kt < 14) {                             // refill X slot: chunk kt+2
            const int d2 = (kt + 2) * 64;
            for (int dd = 0; dd < 2; ++dd)
                for (int p = 0; p < 2; ++p)
                    xn[kt & 1][dd * 2 + p] = *(const float4*)(xrow + d2 + dd * 32 + quad * 8 + p * 4);
        }

        for (int dd = 0; dd < 2; ++dd) {
            // prefetch W frags for the NEXT half-step into the other buffer
            // (dd==0 -> (kt,1) into wf[1]; dd==1 -> (kt+1,0) into wf[0])
            if (dd == 0) {
                for (int nt = 0; nt < 8; ++nt)
                    wf[1][nt] = *(const bf16x8*)(wp[nt] + kt * 64 + 32);
            } else if (kt < 15) {
                for (int nt = 0; nt < 8; ++nt)
                    wf[0][nt] = *(const bf16x8*)(wp[nt] + (kt + 1) * 64);
            }

            float4 x0 = xc[dd * 2], x1 = xc[dd * 2 + 1];
            bf16x8 af;
            af[0] = (__bf16)x0.x; af[1] = (__bf16)x0.y; af[2] = (__bf16)x0.z; af[3] = (__bf16)x0.w;
            af[4] = (__bf16)x1.x; af[5] = (__bf16)x1.y; af[6] = (__bf16)x1.z; af[7] = (__bf16)x1.w;
            for (int nt = 0; nt < 8; ++nt)
                acc[nt] = __builtin_amdgcn_mfma_f32_16x16x32_bf16(af, wf[dd][nt], acc[nt], 0, 0, 0);
        }
    }

    // C/D: row = quad*4+r, col = c16 + 16*nt
    if (mat < 2) {
        __bf16* outp = (mat == 0) ? qb : kb;
        for (int nt = 0; nt < 8; ++nt)
            for (int r = 0; r < 4; ++r)
                outp[(size_t)(m0 + quad * 4 + r) * DK_ + nt * 16 + c16] = (__bf16)acc[nt][r];
    } else {
        for (int nt = 0; nt < 8; ++nt)
            for (int r = 0; r < 4; ++r) {
                int row = m0 + quad * 4 + r;
                int b = row >> 12, s = row & (L_ - 1);
                vT[((size_t)b * DV_ + nt * 16 + c16) * L_ + s] = (__bf16)acc[nt][r];
            }
    }
}

// ---------------------------------------------------------------------------
// Kernel 2: flash attention. K/V tiles staged via async DMA into
// double-buffered XOR-swizzled LDS (K: cb^=row&15, V: cb^=row&7); one
// vmcnt(0)+barrier per chunk; next-chunk DMAs in flight across compute.
// ---------------------------------------------------------------------------
__global__ __launch_bounds__(256, 2) void attn_kernel(
    const __bf16* __restrict__ qb, const __bf16* __restrict__ kb,
    const __bf16* __restrict__ vT, const int* __restrict__ mask,
    __bf16* __restrict__ ob_part, float* __restrict__ ml_part)
{
    __shared__ __bf16 kbuf[2][64 * 128];   // 16 KB x2
    __shared__ __bf16 vbuf[2][128 * 64];   // 16 KB x2
    __shared__ __bf16 p_lds[4][16 * 76];   // 9728 B  (total 75264 -> 2 blk/CU)

    const int t    = threadIdx.x;
    const int w    = t >> 6;
    const int l    = t & 63;
    const int quad = l >> 4;
    const int c16  = l & 15;

    const int combo = blockIdx.x & 15;     // XCD pinning: 1 batch x 2 ranges/XCD
    const int b     = combo & 3;
    const int ks    = combo >> 2;
    const int qt    = blockIdx.x >> 4;
    const int m0    = qt * 64 + w * 16;
    const size_t bL = (size_t)b * L_;
    const int kbase = ks * (L_ / KS_);

    // DMA source pointers (XOR-swizzled so frag reads are 2-way/free)
    const __bf16* kg[4];
    const __bf16* vg[4];
    for (int i = 0; i < 4; ++i) {
        int kr  = (w * 4 + i) * 4 + (l >> 4);          // 0..63
        int klc = (l & 15) ^ (kr & 15);
        kg[i] = kb + (bL + kbase + kr) * DK_ + klc * 8;
        int vr  = (w * 4 + i) * 8 + (l >> 3);          // 0..127
        int vlc = (l & 7) ^ (vr & 7);
        vg[i] = vT + ((size_t)b * DV_ + vr) * L_ + kbase + vlc * 8;
    }

    bf16x8 qf[4];
    {
        const __bf16* qrow = &qb[(bL + m0 + c16) * DK_];
        for (int dt = 0; dt < 4; ++dt)
            qf[dt] = *(const bf16x8*)&qrow[dt * 32 + quad * 8];
    }

    // vectorized mask ballot: bit sc set iff all 64 keys of chunk sc valid
    unsigned int mbits = 0;
    for (int g = 0; g < 4; ++g) {
        const int4 mv = *(const int4*)&mask[bL + kbase + g * 256 + l * 4];
        bool ok = (mv.x == 1) && (mv.y == 1) && (mv.z == 1) && (mv.w == 1);
        unsigned long long bm = __ballot(ok);
        for (int cc = 0; cc < 4; ++cc)
            if (((bm >> (16 * cc)) & 0xFFFFull) == 0xFFFFull)
                mbits |= 1u << (g * 4 + cc);
    }

    bf16x8 onesv;
    for (int i = 0; i < 8; ++i) onesv[i] = (__bf16)1.0f;

    f32x4 o[8], osum;
    for (int i = 0; i < 8; ++i) o[i] = {0.f, 0.f, 0.f, 0.f};
    osum = {0.f, 0.f, 0.f, 0.f};
    float mst[4];
    for (int r = 0; r < 4; ++r) mst[r] = -1e30f;

    // prologue: DMA chunk 0 into buffer 0; full drain
    for (int i = 0; i < 4; ++i) dma16(kg[i], &kbuf[0][(w * 4 + i) * 512]);
    for (int i = 0; i < 4; ++i) dma16(vg[i], &vbuf[0][(w * 4 + i) * 512]);
    WAITBAR0();

    for (int sc = 0; sc < (L_ / KS_) / 64; ++sc) {   // 16 chunks
        const int cur = sc & 1, nxt = cur ^ 1;
        if (sc < 15) {                               // DMA chunk sc+1
            for (int i = 0; i < 4; ++i)
                dma16(kg[i] + (size_t)(sc + 1) * 64 * DK_, &kbuf[nxt][(w * 4 + i) * 512]);
            for (int i = 0; i < 4; ++i)
                dma16(vg[i] + (sc + 1) * 64, &vbuf[nxt][(w * 4 + i) * 512]);
        }

        // ---- S = q . k^T  (q pre-scaled by 1/sqrt(dk)) ----
        f32x4 sacc[4];
        for (int nt = 0; nt < 4; ++nt) sacc[nt] = {0.f, 0.f, 0.f, 0.f};
        for (int dt = 0; dt < 4; ++dt)
            for (int nt = 0; nt < 4; ++nt) {
                bf16x8 kf = *(const bf16x8*)
                    &kbuf[cur][(nt * 16 + c16) * 128 + (((dt * 4 + quad) ^ c16) << 3)];
                sacc[nt] = __builtin_amdgcn_mfma_f32_16x16x32_bf16(qf[dt], kf, sacc[nt], 0, 0, 0);
            }

        if (!((mbits >> sc) & 1)) {         // slow path (never in this bench)
            const int s0 = kbase + sc * 64;
            for (int nt = 0; nt < 4; ++nt) {
                int mk = mask[bL + s0 + nt * 16 + c16];
                for (int r = 0; r < 4; ++r)
                    if (mk != 1) sacc[nt][r] = -1e30f;
            }
        }

        // ---- online softmax: DPP max-reduce; lazy rescale ----
        float nm[4];
        bool up = false;
        for (int r = 0; r < 4; ++r) {
            float cm = fmaxf(fmaxf(sacc[0][r], sacc[1][r]), fmaxf(sacc[2][r], sacc[3][r]));
            cm = rowmax_dpp(cm);
            nm[r] = fmaxf(mst[r], cm);
            up |= (nm[r] > mst[r]);
        }
        if (__ballot(up)) {
            float alpha[4];
            for (int r = 0; r < 4; ++r) {
                alpha[r] = __expf(mst[r] - nm[r]);
                mst[r] = nm[r];
            }
            for (int vt = 0; vt < 8; ++vt)
                for (int r = 0; r < 4; ++r) o[vt][r] *= alpha[r];
            for (int r = 0; r < 4; ++r) osum[r] *= alpha[r];
        }

        for (int r = 0; r < 4; ++r)
            for (int nt = 0; nt < 4; ++nt) {
                float p = __expf(sacc[nt][r] - nm[r]);
                p_lds[w][(quad * 4 + r) * 76 + nt * 16 + c16] = (__bf16)p;
            }
        __asm__ volatile("s_waitcnt lgkmcnt(0)" ::: "memory");  // P visible (wave-local)

        // ---- O += P.V ; osum += P.1 ----
        for (int kt = 0; kt < 2; ++kt) {
            bf16x8 pf = *(const bf16x8*)&p_lds[w][c16 * 76 + kt * 32 + quad * 8];
            for (int vt = 0; vt < 8; ++vt) {
                bf16x8 vf = *(const bf16x8*)
                    &vbuf[cur][(vt * 16 + c16) * 64 + (((kt * 4 + quad) ^ (c16 & 7)) << 3)];
                o[vt] = __builtin_amdgcn_mfma_f32_16x16x32_bf16(pf, vf, o[vt], 0, 0, 0);
            }
            osum = __builtin_amdgcn_mfma_f32_16x16x32_bf16(pf, onesv, osum, 0, 0, 0);
        }

        if (sc < 15) WAITBAR0();            // next chunk's DMAs complete + barrier
    }

    // ---- write this split's partial (unnormalized o, m, l=osum) ----
    __bf16* op = ob_part + ((size_t)ks * ROWS_ + bL + m0) * DV_;
    for (int vt = 0; vt < 8; ++vt)
        for (int r = 0; r < 4; ++r)
            op[(size_t)(quad * 4 + r) * DV_ + vt * 16 + c16] = (__bf16)o[vt][r];
    if (c16 == 0)
        for (int r = 0; r < 4; ++r) {
            size_t row = (size_t)ks * ROWS_ + bL + m0 + quad * 4 + r;
            ml_part[row * 2 + 0] = mst[r];
            ml_part[row * 2 + 1] = osum[r];
        }
}

// ---------------------------------------------------------------------------
// Kernel 3: combine KS partials.
// ---------------------------------------------------------------------------
__global__ __launch_bounds__(256) void combine_kernel(
    const __bf16* __restrict__ ob_part, const float* __restrict__ ml_part,
    float* __restrict__ out)
{
    const int gid = blockIdx.x * 256 + threadIdx.x;
    const int row = gid >> 5;
    const int c4  = (gid & 31) << 2;

    float m[KS_], lv[KS_];
    float M = -1e30f;
    for (int s = 0; s < KS_; ++s) {
        m[s]  = ml_part[((size_t)s * ROWS_ + row) * 2 + 0];
        lv[s] = ml_part[((size_t)s * ROWS_ + row) * 2 + 1];
        M = fmaxf(M, m[s]);
    }
    float Lt = 0.f, acc[4] = {0.f, 0.f, 0.f, 0.f};
    for (int s = 0; s < KS_; ++s) {
        float ws = __expf(m[s] - M);
        Lt += lv[s] * ws;
        const __bf16* op = ob_part + ((size_t)s * ROWS_ + row) * DV_ + c4;
        for (int c = 0; c < 4; ++c) acc[c] += (float)op[c] * ws;
    }
    float rL = 1.0f / Lt;
    for (int c = 0; c < 4; ++c)
        out[(size_t)row * DV_ + c4 + c] = acc[c] * rL;
}

extern "C" void kernel_launch(void* const* d_in, const int* in_sizes, int n_in,
                              void* d_out, int out_size, void* d_ws, size_t ws_size,
                              hipStream_t stream) {
    const float* Q    = (const float*)d_in[0];
    const float* K    = (const float*)d_in[1];
    const float* V    = (const float*)d_in[2];
    const int*   mask = (const int*)d_in[3];
    const float* WQ   = (const float*)d_in[4];
    const float* WK   = (const float*)d_in[5];
    const float* WV   = (const float*)d_in[6];
    float* out = (float*)d_out;

    __bf16* qb = (__bf16*)d_ws;
    __bf16* kb = qb + (size_t)ROWS_ * DK_;
    __bf16* vT = kb + (size_t)ROWS_ * DK_;
    __bf16* WT = vT + (size_t)ROWS_ * DV_;
    __bf16* ob_part = WT + (size_t)3 * DK_ * DM_;
    float*  ml_part = (float*)(ob_part + (size_t)KS_ * ROWS_ * DV_);

    wt_kernel<<<dim3(DM_ / 32, 3), 256, 0, stream>>>(WQ, WK, WV, WT);
    proj_kernel<<<dim3(ROWS_ / 64, 3), 256, 0, stream>>>(Q, K, V, WT, qb, kb, vT);
    attn_kernel<<<dim3((ROWS_ / 64) * KS_), 256, 0, stream>>>(qb, kb, vT, mask, ob_part, ml_part);
    combine_kernel<<<dim3(ROWS_ * 32 / 256), 256, 0, stream>>>(ob_part, ml_part, out);
}

// Round 5
// 292.038 us; speedup vs baseline: 1.1789x; 1.1789x over previous
//
#include <hip/hip_runtime.h>
#include <hip/hip_bf16.h>

#define B_  4
#define L_  4096
#define DM_ 1024
#define DK_ 128
#define DV_ 128
#define KS_ 4
#define ROWS_ (B_ * L_)            // 16384

typedef __bf16 bf16x8 __attribute__((ext_vector_type(8)));
typedef float  f32x4  __attribute__((ext_vector_type(4)));

// async global->LDS DMA, 16 B per lane, no VGPR round-trip.
// LDS dest is wave-uniform base + lane*16; gsrc is per-lane.
__device__ __forceinline__ void dma16(const void* g, void* l) {
    __builtin_amdgcn_global_load_lds(
        (const __attribute__((address_space(1))) void*)g,
        (__attribute__((address_space(3))) void*)l, 16, 0, 0);
}

// order-independent: drain ALL vmem (DMAs + any reg prefetch) + LDS, barrier.
#define WAITBAR0() __asm__ volatile("s_waitcnt vmcnt(0) lgkmcnt(0)\ns_barrier" ::: "memory")

// counted vmem wait + scheduler fence (rule #18: fence AFTER the wait)
#define WAITV(n) do { \
    __asm__ volatile("s_waitcnt vmcnt(" #n ")" ::: "memory"); \
    __builtin_amdgcn_sched_barrier(0); } while (0)

// 4 pinned X loads via inline asm (the compiler cannot flatten these, which
// was the R0-R3 failure: VGPR_Count 44/52 proved every C-level prefetch was
// register-minimized into a load-and-immediately-wait at the consume site).
// R4 CRASH FIX: outputs are EARLY-CLOBBER ("=&v"). These loads are async —
// dest VGPRs are written at data-return while the address pair %4 is re-read
// at issue by loads 2-4. Without "&" the allocator may overlap an output
// quad with the address pair; load 1's return then corrupts the address for
// loads 2-4 -> wild VA -> memory fault (R4's core dump).
// Covers one BK=64 chunk for one lane: offsets {0,16,128,144} B from p.
__device__ __forceinline__ void xload4(const float* p,
                                       f32x4& a, f32x4& b, f32x4& c, f32x4& d) {
    __asm__ volatile(
        "global_load_dwordx4 %0, %4, off\n"
        "global_load_dwordx4 %1, %4, off offset:16\n"
        "global_load_dwordx4 %2, %4, off offset:128\n"
        "global_load_dwordx4 %3, %4, off offset:144\n"
        : "=&v"(a), "=&v"(b), "=&v"(c), "=&v"(d)
        : "v"(p));
}

// max-reduce over the 16-lane group via DPP row_ror (pure VALU)
__device__ __forceinline__ float rowmax_dpp(float v) {
    int x;
    x = __float_as_int(v);
    v = fmaxf(v, __int_as_float(__builtin_amdgcn_update_dpp(x, x, 0x121, 0xF, 0xF, false)));
    x = __float_as_int(v);
    v = fmaxf(v, __int_as_float(__builtin_amdgcn_update_dpp(x, x, 0x122, 0xF, 0xF, false)));
    x = __float_as_int(v);
    v = fmaxf(v, __int_as_float(__builtin_amdgcn_update_dpp(x, x, 0x124, 0xF, 0xF, false)));
    x = __float_as_int(v);
    v = fmaxf(v, __int_as_float(__builtin_amdgcn_update_dpp(x, x, 0x128, 0xF, 0xF, false)));
    return v;
}

// ---------------------------------------------------------------------------
// Kernel 0: transpose+cast W -> WT bf16; WQ pre-scaled by 1/sqrt(dk).
// ---------------------------------------------------------------------------
__global__ __launch_bounds__(256) void wt_kernel(
    const float* __restrict__ WQ, const float* __restrict__ WK,
    const float* __restrict__ WV, __bf16* __restrict__ WT)
{
    const int mat = blockIdx.y;
    const float* W = (mat == 0) ? WQ : (mat == 1) ? WK : WV;
    const float scl = (mat == 0) ? 0.088388347648318447f : 1.0f;
    __bf16* Wt = WT + (size_t)mat * DK_ * DM_;

    __shared__ float lds[DK_][33];
    const int t  = threadIdx.x;
    const int d0 = blockIdx.x * 32;

    for (int i = 0; i < 16; ++i) {
        int idx = i * 256 + t;
        int dd = idx >> 7, n = idx & 127;
        lds[n][dd] = W[(size_t)(d0 + dd) * DK_ + n] * scl;
    }
    __syncthreads();
    for (int i = 0; i < 16; ++i) {
        int idx = i * 256 + t;
        int n = idx >> 5, dd = idx & 31;
        Wt[(size_t)n * DM_ + d0 + dd] = (__bf16)lds[n][dd];
    }
}

// ---------------------------------------------------------------------------
// Kernel 1: projections. v5 = v4 structure with the early-clobber fix.
// W staged in shared LDS (1x W L2-traffic, XOR swizzle as R0) via 3-buffer
// rotation; X loaded by inline-asm dwordx4 into PINNED registers (3
// generations live = 48 VGPR). Per window kt:
//   vmcnt(8) -> barrier -> issue region kt+2 (4 asm X + 4 DMA = 8 vmem ops)
//   -> compute kt (reads buf kt%3; region kt drained by the vmcnt(8)).
// Buffer safety: window kt writes buf (kt+2)%3, reads buf kt%3; last reader
// of (kt+2)%3 was window kt-1, separated by this window's barrier. All X
// offsets (kt*256+{0,16,128,144} <= 3984 B) fit the 13-bit imm -> one
// static per-lane address for all 64 loads.
// ---------------------------------------------------------------------------
__global__ __launch_bounds__(256, 3) void proj_kernel(
    const float* __restrict__ Q, const float* __restrict__ K, const float* __restrict__ V,
    const __bf16* __restrict__ WT,
    __bf16* __restrict__ qb, __bf16* __restrict__ kb, __bf16* __restrict__ vT)
{
    const int mat = blockIdx.y;
    const float* X = (mat == 0) ? Q : (mat == 1) ? K : V;
    const __bf16* Wt = WT + (size_t)mat * DK_ * DM_;

    __shared__ __bf16 wbuf[3][128 * 64];          // 16 KB x3 -> 3 blocks/CU

    const int t    = threadIdx.x;
    const int w    = t >> 6;
    const int l    = t & 63;
    const int quad = l >> 4;
    const int c16  = l & 15;
    const int m0   = blockIdx.x * 64 + w * 16;
    const float* xp = &X[(size_t)(m0 + c16) * DM_] + quad * 8;   // static base

    // DMA sources: instr i covers row (w*4+i)*8 + (l>>3), phys colblk l&7,
    // fetched logical colblk = phys ^ (row&7)  [XOR swizzle]
    const __bf16* wg[4];
    for (int i = 0; i < 4; ++i) {
        int row = (w * 4 + i) * 8 + (l >> 3);
        int lc  = (l & 7) ^ (row & 7);
        wg[i] = Wt + (size_t)row * DM_ + lc * 8;
    }

    f32x4 acc[8];
    for (int i = 0; i < 8; ++i) acc[i] = {0.f, 0.f, 0.f, 0.f};

    f32x4 xr[3][4];           // 3 pinned X generations (static idx via unroll)

#define ISSUE_REGION(reg, kk) do { \
    xload4(xp + (kk) * 64, xr[reg][0], xr[reg][1], xr[reg][2], xr[reg][3]); \
    for (int i_ = 0; i_ < 4; ++i_) \
        dma16(wg[i_] + (kk) * 64, &wbuf[reg][(w * 4 + i_) * 512]); \
} while (0)

    // prologue: regions 0 and 1 in flight (16 vmem ops)
    ISSUE_REGION(0, 0);
    ISSUE_REGION(1, 1);
    __builtin_amdgcn_sched_barrier(0);

#pragma unroll
    for (int kt = 0; kt < 16; ++kt) {             // BK = 64
        const int cur = kt % 3;
        // drain region kt (8 newer ops = region kt+1 may remain in flight)
        if (kt < 15) WAITV(8); else WAITV(0);
        __asm__ volatile("s_barrier" ::: "memory");
        __builtin_amdgcn_sched_barrier(0);

        if (kt < 14) {                             // issue region kt+2
            ISSUE_REGION((kt + 2) % 3, kt + 2);
            __builtin_amdgcn_sched_barrier(0);
        }

        for (int dd = 0; dd < 2; ++dd) {
            f32x4 x0 = xr[cur][dd * 2], x1 = xr[cur][dd * 2 + 1];
            bf16x8 af;
            af[0] = (__bf16)x0[0]; af[1] = (__bf16)x0[1]; af[2] = (__bf16)x0[2]; af[3] = (__bf16)x0[3];
            af[4] = (__bf16)x1[0]; af[5] = (__bf16)x1[1]; af[6] = (__bf16)x1[2]; af[7] = (__bf16)x1[3];
            for (int nt = 0; nt < 8; ++nt) {
                bf16x8 bfv = *(const bf16x8*)
                    &wbuf[cur][(nt * 16 + c16) * 64 + (((dd * 4 + quad) ^ (c16 & 7)) << 3)];
                acc[nt] = __builtin_amdgcn_mfma_f32_16x16x32_bf16(af, bfv, acc[nt], 0, 0, 0);
            }
        }
    }
#undef ISSUE_REGION

    // C/D: row = quad*4+r, col = c16 + 16*nt
    if (mat < 2) {
        __bf16* outp = (mat == 0) ? qb : kb;
        for (int nt = 0; nt < 8; ++nt)
            for (int r = 0; r < 4; ++r)
                outp[(size_t)(m0 + quad * 4 + r) * DK_ + nt * 16 + c16] = (__bf16)acc[nt][r];
    } else {
        for (int nt = 0; nt < 8; ++nt)
            for (int r = 0; r < 4; ++r) {
                int row = m0 + quad * 4 + r;
                int b = row >> 12, s = row & (L_ - 1);
                vT[((size_t)b * DV_ + nt * 16 + c16) * L_ + s] = (__bf16)acc[nt][r];
            }
    }
}

// ---------------------------------------------------------------------------
// Kernel 2: flash attention. K/V tiles staged via async DMA into
// double-buffered XOR-swizzled LDS (K: cb^=row&15, V: cb^=row&7); one
// vmcnt(0)+barrier per chunk; next-chunk DMAs in flight across compute.
// ---------------------------------------------------------------------------
__global__ __launch_bounds__(256, 2) void attn_kernel(
    const __bf16* __restrict__ qb, const __bf16* __restrict__ kb,
    const __bf16* __restrict__ vT, const int* __restrict__ mask,
    __bf16* __restrict__ ob_part, float* __restrict__ ml_part)
{
    __shared__ __bf16 kbuf[2][64 * 128];   // 16 KB x2
    __shared__ __bf16 vbuf[2][128 * 64];   // 16 KB x2
    __shared__ __bf16 p_lds[4][16 * 76];   // 9728 B  (total 75264 -> 2 blk/CU)

    const int t    = threadIdx.x;
    const int w    = t >> 6;
    const int l    = t & 63;
    const int quad = l >> 4;
    const int c16  = l & 15;

    const int combo = blockIdx.x & 15;     // XCD pinning: 1 batch x 2 ranges/XCD
    const int b     = combo & 3;
    const int ks    = combo >> 2;
    const int qt    = blockIdx.x >> 4;
    const int m0    = qt * 64 + w * 16;
    const size_t bL = (size_t)b * L_;
    const int kbase = ks * (L_ / KS_);

    // DMA source pointers (XOR-swizzled so frag reads are 2-way/free)
    const __bf16* kg[4];
    const __bf16* vg[4];
    for (int i = 0; i < 4; ++i) {
        int kr  = (w * 4 + i) * 4 + (l >> 4);          // 0..63
        int klc = (l & 15) ^ (kr & 15);
        kg[i] = kb + (bL + kbase + kr) * DK_ + klc * 8;
        int vr  = (w * 4 + i) * 8 + (l >> 3);          // 0..127
        int vlc = (l & 7) ^ (vr & 7);
        vg[i] = vT + ((size_t)b * DV_ + vr) * L_ + kbase + vlc * 8;
    }

    bf16x8 qf[4];
    {
        const __bf16* qrow = &qb[(bL + m0 + c16) * DK_];
        for (int dt = 0; dt < 4; ++dt)
            qf[dt] = *(const bf16x8*)&qrow[dt * 32 + quad * 8];
    }

    // vectorized mask ballot: bit sc set iff all 64 keys of chunk sc valid
    unsigned int mbits = 0;
    for (int g = 0; g < 4; ++g) {
        const int4 mv = *(const int4*)&mask[bL + kbase + g * 256 + l * 4];
        bool ok = (mv.x == 1) && (mv.y == 1) && (mv.z == 1) && (mv.w == 1);
        unsigned long long bm = __ballot(ok);
        for (int cc = 0; cc < 4; ++cc)
            if (((bm >> (16 * cc)) & 0xFFFFull) == 0xFFFFull)
                mbits |= 1u << (g * 4 + cc);
    }

    bf16x8 onesv;
    for (int i = 0; i < 8; ++i) onesv[i] = (__bf16)1.0f;

    f32x4 o[8], osum;
    for (int i = 0; i < 8; ++i) o[i] = {0.f, 0.f, 0.f, 0.f};
    osum = {0.f, 0.f, 0.f, 0.f};
    float mst[4];
    for (int r = 0; r < 4; ++r) mst[r] = -1e30f;

    // prologue: DMA chunk 0 into buffer 0; full drain
    for (int i = 0; i < 4; ++i) dma16(kg[i], &kbuf[0][(w * 4 + i) * 512]);
    for (int i = 0; i < 4; ++i) dma16(vg[i], &vbuf[0][(w * 4 + i) * 512]);
    WAITBAR0();

    for (int sc = 0; sc < (L_ / KS_) / 64; ++sc) {   // 16 chunks
        const int cur = sc & 1, nxt = cur ^ 1;
        if (sc < 15) {                               // DMA chunk sc+1
            for (int i = 0; i < 4; ++i)
                dma16(kg[i] + (size_t)(sc + 1) * 64 * DK_, &kbuf[nxt][(w * 4 + i) * 512]);
            for (int i = 0; i < 4; ++i)
                dma16(vg[i] + (sc + 1) * 64, &vbuf[nxt][(w * 4 + i) * 512]);
        }

        // ---- S = q . k^T  (q pre-scaled by 1/sqrt(dk)) ----
        f32x4 sacc[4];
        for (int nt = 0; nt < 4; ++nt) sacc[nt] = {0.f, 0.f, 0.f, 0.f};
        for (int dt = 0; dt < 4; ++dt)
            for (int nt = 0; nt < 4; ++nt) {
                bf16x8 kf = *(const bf16x8*)
                    &kbuf[cur][(nt * 16 + c16) * 128 + (((dt * 4 + quad) ^ c16) << 3)];
                sacc[nt] = __builtin_amdgcn_mfma_f32_16x16x32_bf16(qf[dt], kf, sacc[nt], 0, 0, 0);
            }

        if (!((mbits >> sc) & 1)) {         // slow path (never in this bench)
            const int s0 = kbase + sc * 64;
            for (int nt = 0; nt < 4; ++nt) {
                int mk = mask[bL + s0 + nt * 16 + c16];
                for (int r = 0; r < 4; ++r)
                    if (mk != 1) sacc[nt][r] = -1e30f;
            }
        }

        // ---- online softmax: DPP max-reduce; lazy rescale ----
        float nm[4];
        bool up = false;
        for (int r = 0; r < 4; ++r) {
            float cm = fmaxf(fmaxf(sacc[0][r], sacc[1][r]), fmaxf(sacc[2][r], sacc[3][r]));
            cm = rowmax_dpp(cm);
            nm[r] = fmaxf(mst[r], cm);
            up |= (nm[r] > mst[r]);
        }
        if (__ballot(up)) {
            float alpha[4];
            for (int r = 0; r < 4; ++r) {
                alpha[r] = __expf(mst[r] - nm[r]);
                mst[r] = nm[r];
            }
            for (int vt = 0; vt < 8; ++vt)
                for (int r = 0; r < 4; ++r) o[vt][r] *= alpha[r];
            for (int r = 0; r < 4; ++r) osum[r] *= alpha[r];
        }

        for (int r = 0; r < 4; ++r)
            for (int nt = 0; nt < 4; ++nt) {
                float p = __expf(sacc[nt][r] - nm[r]);
                p_lds[w][(quad * 4 + r) * 76 + nt * 16 + c16] = (__bf16)p;
            }
        __asm__ volatile("s_waitcnt lgkmcnt(0)" ::: "memory");  // P visible (wave-local)

        // ---- O += P.V ; osum += P.1 ----
        for (int kt = 0; kt < 2; ++kt) {
            bf16x8 pf = *(const bf16x8*)&p_lds[w][c16 * 76 + kt * 32 + quad * 8];
            for (int vt = 0; vt < 8; ++vt) {
                bf16x8 vf = *(const bf16x8*)
                    &vbuf[cur][(vt * 16 + c16) * 64 + (((kt * 4 + quad) ^ (c16 & 7)) << 3)];
                o[vt] = __builtin_amdgcn_mfma_f32_16x16x32_bf16(pf, vf, o[vt], 0, 0, 0);
            }
            osum = __builtin_amdgcn_mfma_f32_16x16x32_bf16(pf, onesv, osum, 0, 0, 0);
        }

        if (sc < 15) WAITBAR0();            // next chunk's DMAs complete + barrier
    }

    // ---- write this split's partial (unnormalized o, m, l=osum) ----
    __bf16* op = ob_part + ((size_t)ks * ROWS_ + bL + m0) * DV_;
    for (int vt = 0; vt < 8; ++vt)
        for (int r = 0; r < 4; ++r)
            op[(size_t)(quad * 4 + r) * DV_ + vt * 16 + c16] = (__bf16)o[vt][r];
    if (c16 == 0)
        for (int r = 0; r < 4; ++r) {
            size_t row = (size_t)ks * ROWS_ + bL + m0 + quad * 4 + r;
            ml_part[row * 2 + 0] = mst[r];
            ml_part[row * 2 + 1] = osum[r];
        }
}

// ---------------------------------------------------------------------------
// Kernel 3: combine KS partials.
// ---------------------------------------------------------------------------
__global__ __launch_bounds__(256) void combine_kernel(
    const __bf16* __restrict__ ob_part, const float* __restrict__ ml_part,
    float* __restrict__ out)
{
    const int gid = blockIdx.x * 256 + threadIdx.x;
    const int row = gid >> 5;
    const int c4  = (gid & 31) << 2;

    float m[KS_], lv[KS_];
    float M = -1e30f;
    for (int s = 0; s < KS_; ++s) {
        m[s]  = ml_part[((size_t)s * ROWS_ + row) * 2 + 0];
        lv[s] = ml_part[((size_t)s * ROWS_ + row) * 2 + 1];
        M = fmaxf(M, m[s]);
    }
    float Lt = 0.f, acc[4] = {0.f, 0.f, 0.f, 0.f};
    for (int s = 0; s < KS_; ++s) {
        float ws = __expf(m[s] - M);
        Lt += lv[s] * ws;
        const __bf16* op = ob_part + ((size_t)s * ROWS_ + row) * DV_ + c4;
        for (int c = 0; c < 4; ++c) acc[c] += (float)op[c] * ws;
    }
    float rL = 1.0f / Lt;
    for (int c = 0; c < 4; ++c)
        out[(size_t)row * DV_ + c4 + c] = acc[c] * rL;
}

extern "C" void kernel_launch(void* const* d_in, const int* in_sizes, int n_in,
                              void* d_out, int out_size, void* d_ws, size_t ws_size,
                              hipStream_t stream) {
    const float* Q    = (const float*)d_in[0];
    const float* K    = (const float*)d_in[1];
    const float* V    = (const float*)d_in[2];
    const int*   mask = (const int*)d_in[3];
    const float* WQ   = (const float*)d_in[4];
    const float* WK   = (const float*)d_in[5];
    const float* WV   = (const float*)d_in[6];
    float* out = (float*)d_out;

    __bf16* qb = (__bf16*)d_ws;
    __bf16* kb = qb + (size_t)ROWS_ * DK_;
    __bf16* vT = kb + (size_t)ROWS_ * DK_;
    __bf16* WT = vT + (size_t)ROWS_ * DV_;
    __bf16* ob_part = WT + (size_t)3 * DK_ * DM_;
    float*  ml_part = (float*)(ob_part + (size_t)KS_ * ROWS_ * DV_);

    wt_kernel<<<dim3(DM_ / 32, 3), 256, 0, stream>>>(WQ, WK, WV, WT);
    proj_kernel<<<dim3(ROWS_ / 64, 3), 256, 0, stream>>>(Q, K, V, WT, qb, kb, vT);
    attn_kernel<<<dim3((ROWS_ / 64) * KS_), 256, 0, stream>>>(qb, kb, vT, mask, ob_part, ml_part);
    combine_kernel<<<dim3(ROWS_ * 32 / 256), 256, 0, stream>>>(ob_part, ml_part, out);
}